// Round 1
// baseline (492.850 us; speedup 1.0000x reference)
//
#include <hip/hip_runtime.h>
#include <hip/hip_bf16.h>

typedef __attribute__((ext_vector_type(8))) short bf16x8;
typedef __attribute__((ext_vector_type(4))) float f32x4;
typedef __attribute__((ext_vector_type(4))) unsigned short u16x4;

#define MFMA16(a, b, c) __builtin_amdgcn_mfma_f32_16x16x32_bf16(a, b, c, 0, 0, 0)

#define SCALE 0.21022410381342865f /* 512^(-1/4) */

__device__ __forceinline__ unsigned short f2bf(float f) {
    union { float f; unsigned u; } v; v.f = f;
    unsigned r = v.u + 0x7FFF + ((v.u >> 16) & 1);
    return (unsigned short)(r >> 16);
}

// ---------------------------------------------------------------- GroupNorm
// block = (b, g); 256 threads; reduce 64*64*16 elems; write bf16 x_hat
__global__ __launch_bounds__(256) void gn_kernel(
    const float* __restrict__ x, const float* __restrict__ gamma,
    const float* __restrict__ beta, unsigned short* __restrict__ xn)
{
    int b = blockIdx.x >> 5, g = blockIdx.x & 31;
    int t = threadIdx.x;
    const float4* xf4 = (const float4*)x;
    size_t base4 = (size_t)b * (4096 * 128) + g * 4;

    float s = 0.f, ss = 0.f;
    for (int i = 0; i < 64; ++i) {
        int flat = i * 256 + t;
        int hw = flat >> 2, c4 = flat & 3;
        float4 v = xf4[base4 + (size_t)hw * 128 + c4];
        s  += v.x + v.y + v.z + v.w;
        ss += v.x * v.x + v.y * v.y + v.z * v.z + v.w * v.w;
    }
    for (int m = 32; m >= 1; m >>= 1) { s += __shfl_xor(s, m); ss += __shfl_xor(ss, m); }
    __shared__ float rs_[4], rss_[4];
    int wv = t >> 6;
    if ((t & 63) == 0) { rs_[wv] = s; rss_[wv] = ss; }
    __syncthreads();
    float tot  = rs_[0] + rs_[1] + rs_[2] + rs_[3];
    float tot2 = rss_[0] + rss_[1] + rss_[2] + rss_[3];
    float mean = tot * (1.f / 65536.f);
    float var  = tot2 * (1.f / 65536.f) - mean * mean;
    float rstd = rsqrtf(var + 1e-6f);

    const float4* g4 = (const float4*)gamma;
    const float4* b4 = (const float4*)beta;
    for (int i = 0; i < 64; ++i) {
        int flat = i * 256 + t;
        int hw = flat >> 2, c4 = flat & 3;
        float4 v  = xf4[base4 + (size_t)hw * 128 + c4];
        float4 gm = g4[g * 4 + c4], bt = b4[g * 4 + c4];
        u16x4 o;
        o.x = f2bf((v.x - mean) * rstd * gm.x + bt.x);
        o.y = f2bf((v.y - mean) * rstd * gm.y + bt.y);
        o.z = f2bf((v.z - mean) * rstd * gm.z + bt.z);
        o.w = f2bf((v.w - mean) * rstd * gm.w + bt.w);
        size_t m_ = (size_t)(b * 4096 + hw);
        *(u16x4*)&xn[m_ * 512 + g * 16 + c4 * 4] = o;
    }
}

// ------------------------------------------------- weight prep: W^T as bf16
__global__ __launch_bounds__(256) void wprep(
    const float* __restrict__ Wq, const float* __restrict__ Wk,
    const float* __restrict__ Wv, const float* __restrict__ Wp,
    unsigned short* __restrict__ wqkvt, unsigned short* __restrict__ wpt)
{
    int idx = blockIdx.x * 256 + threadIdx.x; // 1,048,576 total
    if (idx < 786432) {
        int n = idx >> 9, k = idx & 511;
        int j = n >> 9, nn = n & 511;
        const float* W = (j == 0) ? Wq : (j == 1) ? Wk : Wv;
        wqkvt[idx] = f2bf(W[k * 512 + nn]);
    } else {
        int i2 = idx - 786432;
        int n = i2 >> 9, k = i2 & 511;
        wpt[i2] = f2bf(Wp[k * 512 + n]);
    }
}

// ------------------------------------------------------------- bf16 GEMM
// C[m][n] = A[m][:] . Bt[n][:]   (A: [M][512] bf16, Bt: [N][512] bf16)
// MODE 0: N=1536 (q|k|v), epilogue bias + scale, bf16 out, row stride 1536
// MODE 1: N=512 (proj), epilogue bias + residual, f32 out
template <int MODE>
__global__ __launch_bounds__(256) void gemm_kernel(
    const unsigned short* __restrict__ A, const unsigned short* __restrict__ Bt,
    const float* __restrict__ bias_q, const float* __restrict__ bias_k,
    const float* __restrict__ bias_v, const float* __restrict__ bias_p,
    const float* __restrict__ resid,
    unsigned short* __restrict__ Cbf, float* __restrict__ Cf)
{
    const int K = 512;
    int m0 = blockIdx.x * 128;
    int n0 = blockIdx.y * 128;
    int t = threadIdx.x;
    int l = t & 63, w = t >> 6;
    int wm = w >> 1, wn = w & 1;
    int lr = l & 15, lg = l >> 4;

    __shared__ unsigned short As[128][72];
    __shared__ unsigned short Bs[128][72];

    f32x4 acc[4][4];
    for (int i = 0; i < 4; ++i)
        for (int j = 0; j < 4; ++j) acc[i][j] = f32x4{0.f, 0.f, 0.f, 0.f};

    for (int k0 = 0; k0 < K; k0 += 64) {
        for (int c = 0; c < 4; ++c) {
            int flat = c * 256 + t;
            int row = flat >> 3, kc = (flat & 7) * 8;
            *(bf16x8*)&As[row][kc] = *(const bf16x8*)&A[(size_t)(m0 + row) * K + k0 + kc];
            *(bf16x8*)&Bs[row][kc] = *(const bf16x8*)&Bt[(size_t)(n0 + row) * K + k0 + kc];
        }
        __syncthreads();
        for (int ks = 0; ks < 2; ++ks) {
            bf16x8 af[4], bfr[4];
            for (int mi = 0; mi < 4; ++mi)
                af[mi] = *(bf16x8*)&As[wm * 64 + mi * 16 + lr][ks * 32 + lg * 8];
            for (int ni = 0; ni < 4; ++ni)
                bfr[ni] = *(bf16x8*)&Bs[wn * 64 + ni * 16 + lr][ks * 32 + lg * 8];
            for (int mi = 0; mi < 4; ++mi)
                for (int ni = 0; ni < 4; ++ni)
                    acc[mi][ni] = MFMA16(af[mi], bfr[ni], acc[mi][ni]);
        }
        __syncthreads();
    }

    for (int mi = 0; mi < 4; ++mi)
        for (int ni = 0; ni < 4; ++ni)
            for (int r = 0; r < 4; ++r) {
                int row = m0 + wm * 64 + mi * 16 + lg * 4 + r;
                int col = n0 + wn * 64 + ni * 16 + lr;
                float val = acc[mi][ni][r];
                if (MODE == 0) {
                    float bias, scl;
                    if (col < 512)       { bias = bias_q[col];        scl = SCALE; }
                    else if (col < 1024) { bias = bias_k[col - 512];  scl = SCALE; }
                    else                 { bias = bias_v[col - 1024]; scl = 1.0f;  }
                    Cbf[(size_t)row * 1536 + col] = f2bf((val + bias) * scl);
                } else {
                    Cf[(size_t)row * 512 + col] =
                        val + bias_p[col] + resid[(size_t)row * 512 + col];
                }
            }
}

// ------------------------------------------------ V transpose to [b][d][n]
__global__ __launch_bounds__(256) void vtrans(
    const unsigned short* __restrict__ qkv, unsigned short* __restrict__ vT)
{
    int n0 = blockIdx.x * 64, d0 = blockIdx.y * 64, b = blockIdx.z;
    int t = threadIdx.x;
    __shared__ unsigned short tile[64][72];
    for (int c = 0; c < 2; ++c) {
        int flat = c * 256 + t;
        int r = flat >> 3, cc = (flat & 7) * 8;
        *(bf16x8*)&tile[r][cc] =
            *(const bf16x8*)&qkv[(size_t)(b * 4096 + n0 + r) * 1536 + 1024 + d0 + cc];
    }
    __syncthreads();
    for (int c = 0; c < 2; ++c) {
        int flat = c * 256 + t;
        int dr = flat >> 3, nc = (flat & 7) * 8;
        bf16x8 v;
        for (int j = 0; j < 8; ++j) v[j] = (short)tile[nc + j][dr];
        *(bf16x8*)&vT[((size_t)b * 512 + d0 + dr) * 4096 + n0 + nc] = v;
    }
}

// ------------------------------------------------------- flash attention
// grid (64 q-tiles, 4 batch), 256 thr (4 waves x 16 q-rows), KVBLK=32, D=512
__global__ __launch_bounds__(256, 1) void attn_kernel(
    const unsigned short* __restrict__ qkv, // [16384][1536] (q|k|v)
    const unsigned short* __restrict__ vT,  // [4][512][4096]
    unsigned short* __restrict__ out)       // [16384][512]
{
    int n0 = blockIdx.x * 64;
    int b = blockIdx.y;
    int t = threadIdx.x, l = t & 63, w = t >> 6;
    int lr = l & 15, lg = l >> 4;

    __shared__ unsigned short Ks[32][520];
    __shared__ unsigned short Vs[512][40];
    __shared__ unsigned short Ps[64][40];

    // Q rows (n0 + w*16 + lr) hoisted to registers: 16 k-step fragments
    bf16x8 qf[16];
    {
        const unsigned short* qrow = qkv + (size_t)(b * 4096 + n0 + w * 16 + lr) * 1536;
        for (int ks = 0; ks < 16; ++ks)
            qf[ks] = *(const bf16x8*)&qrow[ks * 32 + lg * 8];
    }
    f32x4 o[32];
    for (int i = 0; i < 32; ++i) o[i] = f32x4{0.f, 0.f, 0.f, 0.f};
    float m_r[4] = {-1e30f, -1e30f, -1e30f, -1e30f};
    float l_r[4] = {0.f, 0.f, 0.f, 0.f};

    for (int kv0 = 0; kv0 < 4096; kv0 += 32) {
        // stage K rows (coalesced b128 -> b128)
        for (int c = 0; c < 8; ++c) {
            int flat = c * 256 + t;
            int row = flat >> 6, kc = (flat & 63) * 8;
            *(bf16x8*)&Ks[row][kc] =
                *(const bf16x8*)&qkv[(size_t)(b * 4096 + kv0 + row) * 1536 + 512 + kc];
        }
        // stage V^T tile [512][32]
        for (int c = 0; c < 8; ++c) {
            int flat = c * 256 + t;
            int d = flat >> 2, kc = (flat & 3) * 8;
            *(bf16x8*)&Vs[d][kc] =
                *(const bf16x8*)&vT[((size_t)b * 512 + d) * 4096 + kv0 + kc];
        }
        __syncthreads();

        // QK^T : S[16][32] per wave
        f32x4 s0 = {0.f, 0.f, 0.f, 0.f}, s1 = {0.f, 0.f, 0.f, 0.f};
        for (int ks = 0; ks < 16; ++ks) {
            bf16x8 k0f = *(bf16x8*)&Ks[lr][ks * 32 + lg * 8];
            bf16x8 k1f = *(bf16x8*)&Ks[16 + lr][ks * 32 + lg * 8];
            s0 = MFMA16(qf[ks], k0f, s0);
            s1 = MFMA16(qf[ks], k1f, s1);
        }

        // online softmax (defer-max, THR=8)
        float pm[4];
        bool ok = true;
        for (int r = 0; r < 4; ++r) {
            float v = fmaxf(s0[r], s1[r]);
            v = fmaxf(v, __shfl_xor(v, 1));
            v = fmaxf(v, __shfl_xor(v, 2));
            v = fmaxf(v, __shfl_xor(v, 4));
            v = fmaxf(v, __shfl_xor(v, 8));
            pm[r] = v;
            ok &= (v - m_r[r] <= 8.0f);
        }
        if (!__all(ok)) {
            float sf[4];
            for (int r = 0; r < 4; ++r) {
                float mnew = fmaxf(m_r[r], pm[r]);
                sf[r] = __expf(m_r[r] - mnew);
                m_r[r] = mnew;
                l_r[r] *= sf[r];
            }
            for (int i = 0; i < 32; ++i)
                for (int r = 0; r < 4; ++r) o[i][r] *= sf[r];
        }
        float p0[4], p1[4];
        for (int r = 0; r < 4; ++r) {
            p0[r] = __expf(s0[r] - m_r[r]);
            p1[r] = __expf(s1[r] - m_r[r]);
            float rs = p0[r] + p1[r];
            rs += __shfl_xor(rs, 1);
            rs += __shfl_xor(rs, 2);
            rs += __shfl_xor(rs, 4);
            rs += __shfl_xor(rs, 8);
            l_r[r] += rs;
        }
        // P -> LDS (re-layout for MFMA A operand)
        for (int r = 0; r < 4; ++r) {
            Ps[w * 16 + lg * 4 + r][lr]      = f2bf(p0[r]);
            Ps[w * 16 + lg * 4 + r][16 + lr] = f2bf(p1[r]);
        }
        __syncthreads();

        // PV : O[16][512] += P[16][32] . V[32][512]
        bf16x8 pa = *(bf16x8*)&Ps[w * 16 + lr][lg * 8];
        for (int nd = 0; nd < 32; ++nd) {
            bf16x8 bv = *(bf16x8*)&Vs[nd * 16 + lr][lg * 8];
            o[nd] = MFMA16(pa, bv, o[nd]);
        }
        __syncthreads();
    }

    float inv[4];
    for (int r = 0; r < 4; ++r) inv[r] = 1.0f / l_r[r];
    for (int nd = 0; nd < 32; ++nd)
        for (int r = 0; r < 4; ++r)
            out[(size_t)(b * 4096 + n0 + w * 16 + lg * 4 + r) * 512 + nd * 16 + lr] =
                f2bf(o[nd][r] * inv[r]);
}

// --------------------------------------------------------------- launcher
extern "C" void kernel_launch(void* const* d_in, const int* in_sizes, int n_in,
                              void* d_out, int out_size, void* d_ws, size_t ws_size,
                              hipStream_t stream)
{
    const float* x     = (const float*)d_in[0];
    const float* gamma = (const float*)d_in[1];
    const float* beta  = (const float*)d_in[2];
    const float* Wq = (const float*)d_in[3];
    const float* bq = (const float*)d_in[4];
    const float* Wk = (const float*)d_in[5];
    const float* bk = (const float*)d_in[6];
    const float* Wv = (const float*)d_in[7];
    const float* bv = (const float*)d_in[8];
    const float* Wp = (const float*)d_in[9];
    const float* bp = (const float*)d_in[10];
    float* out = (float*)d_out;

    unsigned short* xn    = (unsigned short*)d_ws;                 // 16384*512
    unsigned short* wqkvt = xn + (size_t)16384 * 512;              // 1536*512
    unsigned short* wpt   = wqkvt + (size_t)1536 * 512;            // 512*512
    unsigned short* qkv   = wpt + (size_t)512 * 512;               // 16384*1536
    unsigned short* vT    = qkv + (size_t)16384 * 1536;            // 4*512*4096
    unsigned short* attn  = vT + (size_t)4 * 512 * 4096;           // 16384*512

    gn_kernel<<<dim3(128), dim3(256), 0, stream>>>(x, gamma, beta, xn);
    wprep<<<dim3(4096), dim3(256), 0, stream>>>(Wq, Wk, Wv, Wp, wqkvt, wpt);
    gemm_kernel<0><<<dim3(128, 12), dim3(256), 0, stream>>>(
        xn, wqkvt, bq, bk, bv, nullptr, nullptr, qkv, nullptr);
    vtrans<<<dim3(64, 8, 4), dim3(256), 0, stream>>>(qkv, vT);
    attn_kernel<<<dim3(64, 4), dim3(256), 0, stream>>>(qkv, vT, attn);
    gemm_kernel<1><<<dim3(128, 4), dim3(256), 0, stream>>>(
        attn, wpt, nullptr, nullptr, nullptr, bp, x, nullptr, out);
}

// Round 2
// 436.078 us; speedup vs baseline: 1.1302x; 1.1302x over previous
//
#include <hip/hip_runtime.h>
#include <hip/hip_bf16.h>

typedef __attribute__((ext_vector_type(8))) short bf16x8;
typedef __attribute__((ext_vector_type(4))) float f32x4;
typedef __attribute__((ext_vector_type(4))) unsigned short u16x4;

#define MFMA16(a, b, c) __builtin_amdgcn_mfma_f32_16x16x32_bf16(a, b, c, 0, 0, 0)

#define SCALE 0.21022410381342865f /* 512^(-1/4) */

__device__ __forceinline__ unsigned short f2bf(float f) {
    union { float f; unsigned u; } v; v.f = f;
    unsigned r = v.u + 0x7FFF + ((v.u >> 16) & 1);
    return (unsigned short)(r >> 16);
}

typedef __attribute__((address_space(3))) void lds_void;
typedef const __attribute__((address_space(1))) void gbl_void;
__device__ __forceinline__ void g2l16(const void* g, void* l) {
    __builtin_amdgcn_global_load_lds((gbl_void*)g, (lds_void*)l, 16, 0, 0);
}

// ---------------------------------------------------------------- GroupNorm
__global__ __launch_bounds__(256) void gn_kernel(
    const float* __restrict__ x, const float* __restrict__ gamma,
    const float* __restrict__ beta, unsigned short* __restrict__ xn)
{
    int b = blockIdx.x >> 5, g = blockIdx.x & 31;
    int t = threadIdx.x;
    const float4* xf4 = (const float4*)x;
    size_t base4 = (size_t)b * (4096 * 128) + g * 4;

    float s = 0.f, ss = 0.f;
    for (int i = 0; i < 64; ++i) {
        int flat = i * 256 + t;
        int hw = flat >> 2, c4 = flat & 3;
        float4 v = xf4[base4 + (size_t)hw * 128 + c4];
        s  += v.x + v.y + v.z + v.w;
        ss += v.x * v.x + v.y * v.y + v.z * v.z + v.w * v.w;
    }
    for (int m = 32; m >= 1; m >>= 1) { s += __shfl_xor(s, m); ss += __shfl_xor(ss, m); }
    __shared__ float rs_[4], rss_[4];
    int wv = t >> 6;
    if ((t & 63) == 0) { rs_[wv] = s; rss_[wv] = ss; }
    __syncthreads();
    float tot  = rs_[0] + rs_[1] + rs_[2] + rs_[3];
    float tot2 = rss_[0] + rss_[1] + rss_[2] + rss_[3];
    float mean = tot * (1.f / 65536.f);
    float var  = tot2 * (1.f / 65536.f) - mean * mean;
    float rstd = rsqrtf(var + 1e-6f);

    const float4* g4 = (const float4*)gamma;
    const float4* b4 = (const float4*)beta;
    for (int i = 0; i < 64; ++i) {
        int flat = i * 256 + t;
        int hw = flat >> 2, c4 = flat & 3;
        float4 v  = xf4[base4 + (size_t)hw * 128 + c4];
        float4 gm = g4[g * 4 + c4], bt = b4[g * 4 + c4];
        u16x4 o;
        o.x = f2bf((v.x - mean) * rstd * gm.x + bt.x);
        o.y = f2bf((v.y - mean) * rstd * gm.y + bt.y);
        o.z = f2bf((v.z - mean) * rstd * gm.z + bt.z);
        o.w = f2bf((v.w - mean) * rstd * gm.w + bt.w);
        size_t m_ = (size_t)(b * 4096 + hw);
        *(u16x4*)&xn[m_ * 512 + g * 16 + c4 * 4] = o;
    }
}

// ------------------------------------------------- weight prep: W^T as bf16
__global__ __launch_bounds__(256) void wprep(
    const float* __restrict__ Wq, const float* __restrict__ Wk,
    const float* __restrict__ Wv, const float* __restrict__ Wp,
    unsigned short* __restrict__ wqkvt, unsigned short* __restrict__ wpt)
{
    int idx = blockIdx.x * 256 + threadIdx.x; // 1,048,576 total
    if (idx < 786432) {
        int n = idx >> 9, k = idx & 511;
        int j = n >> 9, nn = n & 511;
        const float* W = (j == 0) ? Wq : (j == 1) ? Wk : Wv;
        wqkvt[idx] = f2bf(W[k * 512 + nn]);
    } else {
        int i2 = idx - 786432;
        int n = i2 >> 9, k = i2 & 511;
        wpt[i2] = f2bf(Wp[k * 512 + n]);
    }
}

// ------------------------------------------------------------- bf16 GEMM
template <int MODE>
__global__ __launch_bounds__(256) void gemm_kernel(
    const unsigned short* __restrict__ A, const unsigned short* __restrict__ Bt,
    const float* __restrict__ bias_q, const float* __restrict__ bias_k,
    const float* __restrict__ bias_v, const float* __restrict__ bias_p,
    const float* __restrict__ resid,
    unsigned short* __restrict__ Cbf, float* __restrict__ Cf)
{
    const int K = 512;
    int m0 = blockIdx.x * 128;
    int n0 = blockIdx.y * 128;
    int t = threadIdx.x;
    int l = t & 63, w = t >> 6;
    int wm = w >> 1, wn = w & 1;
    int lr = l & 15, lg = l >> 4;

    __shared__ unsigned short As[128][72];
    __shared__ unsigned short Bs[128][72];

    f32x4 acc[4][4];
    for (int i = 0; i < 4; ++i)
        for (int j = 0; j < 4; ++j) acc[i][j] = f32x4{0.f, 0.f, 0.f, 0.f};

    for (int k0 = 0; k0 < K; k0 += 64) {
        for (int c = 0; c < 4; ++c) {
            int flat = c * 256 + t;
            int row = flat >> 3, kc = (flat & 7) * 8;
            *(bf16x8*)&As[row][kc] = *(const bf16x8*)&A[(size_t)(m0 + row) * K + k0 + kc];
            *(bf16x8*)&Bs[row][kc] = *(const bf16x8*)&Bt[(size_t)(n0 + row) * K + k0 + kc];
        }
        __syncthreads();
        for (int ks = 0; ks < 2; ++ks) {
            bf16x8 af[4], bfr[4];
            for (int mi = 0; mi < 4; ++mi)
                af[mi] = *(bf16x8*)&As[wm * 64 + mi * 16 + lr][ks * 32 + lg * 8];
            for (int ni = 0; ni < 4; ++ni)
                bfr[ni] = *(bf16x8*)&Bs[wn * 64 + ni * 16 + lr][ks * 32 + lg * 8];
            for (int mi = 0; mi < 4; ++mi)
                for (int ni = 0; ni < 4; ++ni)
                    acc[mi][ni] = MFMA16(af[mi], bfr[ni], acc[mi][ni]);
        }
        __syncthreads();
    }

    for (int mi = 0; mi < 4; ++mi)
        for (int ni = 0; ni < 4; ++ni)
            for (int r = 0; r < 4; ++r) {
                int row = m0 + wm * 64 + mi * 16 + lg * 4 + r;
                int col = n0 + wn * 64 + ni * 16 + lr;
                float val = acc[mi][ni][r];
                if (MODE == 0) {
                    float bias, scl;
                    if (col < 512)       { bias = bias_q[col];        scl = SCALE; }
                    else if (col < 1024) { bias = bias_k[col - 512];  scl = SCALE; }
                    else                 { bias = bias_v[col - 1024]; scl = 1.0f;  }
                    Cbf[(size_t)row * 1536 + col] = f2bf((val + bias) * scl);
                } else {
                    Cf[(size_t)row * 512 + col] =
                        val + bias_p[col] + resid[(size_t)row * 512 + col];
                }
            }
}

// ------------------------------------------------ V transpose to [b][d][n]
__global__ __launch_bounds__(256) void vtrans(
    const unsigned short* __restrict__ qkv, unsigned short* __restrict__ vT)
{
    int n0 = blockIdx.x * 64, d0 = blockIdx.y * 64, b = blockIdx.z;
    int t = threadIdx.x;
    __shared__ unsigned short tile[64][72];
    for (int c = 0; c < 2; ++c) {
        int flat = c * 256 + t;
        int r = flat >> 3, cc = (flat & 7) * 8;
        *(bf16x8*)&tile[r][cc] =
            *(const bf16x8*)&qkv[(size_t)(b * 4096 + n0 + r) * 1536 + 1024 + d0 + cc];
    }
    __syncthreads();
    for (int c = 0; c < 2; ++c) {
        int flat = c * 256 + t;
        int dr = flat >> 3, nc = (flat & 7) * 8;
        bf16x8 v;
        for (int j = 0; j < 8; ++j) v[j] = (short)tile[nc + j][dr];
        *(bf16x8*)&vT[((size_t)b * 512 + d0 + dr) * 4096 + n0 + nc] = v;
    }
}

// ------------------------------------------------------- flash attention v2
// grid (64 q-tiles, 4 batch), 256 thr (4 waves x 16 q-rows), KVBLK=32, D=512
// global_load_lds staging, dbuf K/V (distinct arrays, compile-time buf),
// XOR-swizzled linear LDS layouts, 1 barrier per tile.
//
// K LDS layout: slot(row, u) = row*64 + (u ^ (row&7));   u = 16B unit (0..63)
// V LDS layout: slot(d, u)   = (d>>1)*8 + (d&1)*4 + (u ^ ((d>>1)&3)); u 0..3

__device__ __forceinline__ void stage_tile(
    const unsigned short* __restrict__ qkv, const unsigned short* __restrict__ vT,
    unsigned short* ksB, unsigned short* vsB, int b, int kv0, int t)
{
#pragma unroll
    for (int c = 0; c < 8; ++c) {
        int flat = c * 256 + t;
        int row = flat >> 6, unit = flat & 63;
        const unsigned short* src =
            qkv + (size_t)(b * 4096 + kv0 + row) * 1536 + 512 + ((unit ^ (row & 7)) << 3);
        g2l16(src, ksB + (flat << 3));
    }
#pragma unroll
    for (int c = 0; c < 8; ++c) {
        int flat = c * 256 + t;
        int d = ((flat >> 3) << 1) | ((flat >> 2) & 1);
        int u = (flat & 3) ^ ((flat >> 3) & 3);
        const unsigned short* src =
            vT + ((size_t)b * 512 + d) * 4096 + kv0 + (u << 3);
        g2l16(src, vsB + (flat << 3));
    }
}

__global__ __launch_bounds__(256, 1) void attn_kernel(
    const unsigned short* __restrict__ qkv, // [16384][1536] (q|k|v)
    const unsigned short* __restrict__ vT,  // [4][512][4096]
    unsigned short* __restrict__ out)       // [16384][512]
{
    int n0 = blockIdx.x * 64;
    int b = blockIdx.y;
    int t = threadIdx.x, l = t & 63, w = t >> 6;
    int lr = l & 15, lg = l >> 4;

    __shared__ __align__(16) unsigned short Ks0[32 * 512];
    __shared__ __align__(16) unsigned short Ks1[32 * 512];
    __shared__ __align__(16) unsigned short Vs0[512 * 32];
    __shared__ __align__(16) unsigned short Vs1[512 * 32];
    __shared__ unsigned short Ps[64][40];

    // Q rows (n0 + w*16 + lr) hoisted to registers
    bf16x8 qf[16];
    {
        const unsigned short* qrow = qkv + (size_t)(b * 4096 + n0 + w * 16 + lr) * 1536;
#pragma unroll
        for (int ks = 0; ks < 16; ++ks)
            qf[ks] = *(const bf16x8*)&qrow[ks * 32 + lg * 8];
    }
    f32x4 o[32];
#pragma unroll
    for (int i = 0; i < 32; ++i) o[i] = f32x4{0.f, 0.f, 0.f, 0.f};
    float m_r[4] = {-1e30f, -1e30f, -1e30f, -1e30f};
    float l_r[4] = {0.f, 0.f, 0.f, 0.f};

    // per-thread constant pieces of the swizzled read addresses
    const int kswz = lr & 7;
    const int vbase = ((lr >> 1) << 3) + ((lr & 1) << 2) + (lg ^ ((lr >> 1) & 3));

    auto process = [&](const unsigned short* Ks, const unsigned short* Vs) {
        // ---- QK^T : S[16q][32kv] per wave, 4 independent MFMA chains
        f32x4 s0{0.f,0.f,0.f,0.f}, s1{0.f,0.f,0.f,0.f};
        f32x4 s2{0.f,0.f,0.f,0.f}, s3{0.f,0.f,0.f,0.f};
#pragma unroll
        for (int ks = 0; ks < 16; ks += 2) {
            bf16x8 k0 = *(const bf16x8*)&Ks[lr * 512 + (((ks * 4 + lg) ^ kswz) << 3)];
            bf16x8 k1 = *(const bf16x8*)&Ks[(16 + lr) * 512 + (((ks * 4 + lg) ^ kswz) << 3)];
            s0 = MFMA16(qf[ks], k0, s0);
            s1 = MFMA16(qf[ks], k1, s1);
            bf16x8 k2 = *(const bf16x8*)&Ks[lr * 512 + ((((ks + 1) * 4 + lg) ^ kswz) << 3)];
            bf16x8 k3 = *(const bf16x8*)&Ks[(16 + lr) * 512 + ((((ks + 1) * 4 + lg) ^ kswz) << 3)];
            s2 = MFMA16(qf[ks + 1], k2, s2);
            s3 = MFMA16(qf[ks + 1], k3, s3);
        }
        s0 = s0 + s2;
        s1 = s1 + s3;

        // ---- online softmax (defer-max, THR=8)
        float pm[4];
        bool ok = true;
#pragma unroll
        for (int r = 0; r < 4; ++r) {
            float v = fmaxf(s0[r], s1[r]);
            v = fmaxf(v, __shfl_xor(v, 1));
            v = fmaxf(v, __shfl_xor(v, 2));
            v = fmaxf(v, __shfl_xor(v, 4));
            v = fmaxf(v, __shfl_xor(v, 8));
            pm[r] = v;
            ok &= (v - m_r[r] <= 8.0f);
        }
        if (!__all(ok)) {
            float sf[4];
#pragma unroll
            for (int r = 0; r < 4; ++r) {
                float mnew = fmaxf(m_r[r], pm[r]);
                sf[r] = __expf(m_r[r] - mnew);
                m_r[r] = mnew;
                l_r[r] *= sf[r];
            }
#pragma unroll
            for (int i = 0; i < 32; ++i)
#pragma unroll
                for (int r = 0; r < 4; ++r) o[i][r] *= sf[r];
        }
        float p0[4], p1[4];
#pragma unroll
        for (int r = 0; r < 4; ++r) {
            p0[r] = __expf(s0[r] - m_r[r]);
            p1[r] = __expf(s1[r] - m_r[r]);
            float rs = p0[r] + p1[r];
            rs += __shfl_xor(rs, 1);
            rs += __shfl_xor(rs, 2);
            rs += __shfl_xor(rs, 4);
            rs += __shfl_xor(rs, 8);
            l_r[r] += rs;
        }
        // ---- P -> LDS (wave-private rows; no barrier needed)
#pragma unroll
        for (int r = 0; r < 4; ++r) {
            Ps[w * 16 + lg * 4 + r][lr]      = f2bf(p0[r]);
            Ps[w * 16 + lg * 4 + r][16 + lr] = f2bf(p1[r]);
        }
        // ---- PV : O[16][512] += P[16][32] . V[32][512]
        bf16x8 pa = *(const bf16x8*)&Ps[w * 16 + lr][lg * 8];
        const unsigned short* vptr = Vs + (vbase << 3);
#pragma unroll
        for (int nd = 0; nd < 32; ++nd) {
            bf16x8 bv = *(const bf16x8*)&vptr[nd << 9];
            o[nd] = MFMA16(pa, bv, o[nd]);
        }
    };

    stage_tile(qkv, vT, Ks0, Vs0, b, 0, t);
    __syncthreads();

    for (int it = 0; it < 128; it += 2) {
        // prefetch tile it+1 into buf1 while computing buf0
        stage_tile(qkv, vT, Ks1, Vs1, b, (it + 1) * 32, t);
        process(Ks0, Vs0);
        __syncthreads();   // drains vmcnt -> buf1 ready

        if (it + 2 < 128)
            stage_tile(qkv, vT, Ks0, Vs0, b, (it + 2) * 32, t);
        process(Ks1, Vs1);
        __syncthreads();
    }

    float inv[4];
#pragma unroll
    for (int r = 0; r < 4; ++r) inv[r] = 1.0f / l_r[r];
#pragma unroll
    for (int nd = 0; nd < 32; ++nd)
#pragma unroll
        for (int r = 0; r < 4; ++r)
            out[(size_t)(b * 4096 + n0 + w * 16 + lg * 4 + r) * 512 + nd * 16 + lr] =
                f2bf(o[nd][r] * inv[r]);
}

// --------------------------------------------------------------- launcher
extern "C" void kernel_launch(void* const* d_in, const int* in_sizes, int n_in,
                              void* d_out, int out_size, void* d_ws, size_t ws_size,
                              hipStream_t stream)
{
    const float* x     = (const float*)d_in[0];
    const float* gamma = (const float*)d_in[1];
    const float* beta  = (const float*)d_in[2];
    const float* Wq = (const float*)d_in[3];
    const float* bq = (const float*)d_in[4];
    const float* Wk = (const float*)d_in[5];
    const float* bk = (const float*)d_in[6];
    const float* Wv = (const float*)d_in[7];
    const float* bv = (const float*)d_in[8];
    const float* Wp = (const float*)d_in[9];
    const float* bp = (const float*)d_in[10];
    float* out = (float*)d_out;

    unsigned short* xn    = (unsigned short*)d_ws;                 // 16384*512
    unsigned short* wqkvt = xn + (size_t)16384 * 512;              // 1536*512
    unsigned short* wpt   = wqkvt + (size_t)1536 * 512;            // 512*512
    unsigned short* qkv   = wpt + (size_t)512 * 512;               // 16384*1536
    unsigned short* vT    = qkv + (size_t)16384 * 1536;            // 4*512*4096
    unsigned short* attn  = vT + (size_t)4 * 512 * 4096;           // 16384*512

    gn_kernel<<<dim3(128), dim3(256), 0, stream>>>(x, gamma, beta, xn);
    wprep<<<dim3(4096), dim3(256), 0, stream>>>(Wq, Wk, Wv, Wp, wqkvt, wpt);
    gemm_kernel<0><<<dim3(128, 12), dim3(256), 0, stream>>>(
        xn, wqkvt, bq, bk, bv, nullptr, nullptr, qkv, nullptr);
    vtrans<<<dim3(64, 8, 4), dim3(256), 0, stream>>>(qkv, vT);
    attn_kernel<<<dim3(64, 4), dim3(256), 0, stream>>>(qkv, vT, attn);
    gemm_kernel<1><<<dim3(128, 4), dim3(256), 0, stream>>>(
        attn, wpt, nullptr, nullptr, nullptr, bp, x, nullptr, out);
}